// Round 10
// baseline (297.277 us; speedup 1.0000x reference)
//
#include <hip/hip_runtime.h>

typedef __attribute__((ext_vector_type(8))) short short8;
typedef __attribute__((ext_vector_type(4))) float f32x4;
typedef __attribute__((ext_vector_type(4))) unsigned short bfu4;

#define MFMA(a, b, c) __builtin_amdgcn_mfma_f32_16x16x32_bf16((a), (b), (c), 0, 0, 0)
#define SCALE 0.17677669529663687f

__device__ __forceinline__ unsigned short f2bf(float f) {
    union { float f; unsigned u; } v; v.f = f;
    unsigned r = v.u + 0x7fffu + ((v.u >> 16) & 1u);
    return (unsigned short)(r >> 16);
}

// ---- prep: R3-verbatim weight fragment layout (128KB in d_ws) ----
__global__ __launch_bounds__(256)
void prep_w(const float* __restrict__ qkv_w, const float* __restrict__ proj_w,
            unsigned short* __restrict__ wf)
{
    int id = blockIdx.x * 256 + threadIdx.x;          // 0..65535
    int j  = id & 7;
    int l  = (id >> 3) & 63;
    int ks = (id >> 9) & 3;
    int row16 = l & 15;
    int kk = ks * 32 + ((l >> 4) << 3) + j;
    if (id < 49152) {
        int mt = id >> 11;                            // 0..23
        wf[id] = f2bf(qkv_w[(mt * 16 + row16) * 128 + kk]);
    } else {
        int mt = (id - 49152) >> 11;                  // 0..7
        wf[id] = f2bf(proj_w[(mt * 16 + row16) * 128 + kk]);
    }
}

// ---- main: one block/window, TWO head-pair passes through 40KB LDS ----
// [0,16K)  xs [64n][128c] bf16 swz ^((n&7)<<4)  -> aoT (same layout) -> out f32 staging
// [16K,32K) qkT per pass: [2 hh][64n][64col] (q cols 0..31, k cols 32..63) -> P
// [32K,40K) Vt per pass: [2 hh][32d][64m] swz ^((d&7)<<4)
#define QKO 16384
#define VTO2 32768
#define LDS_BYTES 40960

__global__ __launch_bounds__(256, 4)
void win_attn_mfma(const float* __restrict__ x, const float* __restrict__ mask,
                   const float* __restrict__ qkv_b, const float* __restrict__ proj_b,
                   const float* __restrict__ bt, const unsigned short* __restrict__ wf,
                   float* __restrict__ out)
{
    extern __shared__ char smem[];
    const int b = blockIdx.x, tid = threadIdx.x;
    const int w = tid >> 6, l = tid & 63, g = l >> 4, lr = l & 15;
    const int wi = b & 63;
    const int hh = w >> 1;          // local head (0..1) within the pass
    const int nh = w & 1;           // n-half (rows nh*32 .. nh*32+31)

    // ---- stage x (float4 loads + f2bf; R3 layout) ----
    {
        const float4* xb4 = (const float4*)(x + (size_t)b * 6272);
        for (int i = tid; i < 1568; i += 256) {
            float4 v4 = xb4[i];
            float vals[4] = {v4.x, v4.y, v4.z, v4.w};
            int r0 = i * 4;
            #pragma unroll
            for (int e = 0; e < 4; ++e) {
                int r = r0 + e;
                int c = (int)(((unsigned)r * 21400u) >> 20);   // r/49, exact for r<6272
                int n = r - c * 49;
                *(unsigned short*)(smem + n * 256 + ((c * 2) ^ ((n & 7) << 4))) =
                    f2bf(vals[e]);
            }
        }
        for (int i = tid; i < 1920; i += 256) {                // zero pad rows 49..63
            int n = 49 + (i >> 7), c = i & 127;
            *(unsigned short*)(smem + n * 256 + ((c * 2) ^ ((n & 7) << 4))) = 0;
        }
    }
    __syncthreads();   // B1

    const short8* wfa = (const short8*)wf;
    f32x4 Osav[2][2][2];   // [pass][mt][dt] — static indices only

    #pragma unroll
    for (int p2 = 0; p2 < 2; ++p2) {
        // ---- phase A: wave w handles parts j = 3w..3w+2 of this pass's 12 ----
        #pragma unroll
        for (int i = 0; i < 3; ++i) {
            const int j = w * 3 + i;            // 0..11
            const int typ = j >> 2;             // 0=q, 1=k, 2=v
            const int jj = j & 3;
            const int ph = jj >> 1;             // local head of this part
            const int blk = jj & 1;             // 16-wide d-block
            const int T = typ * 8 + p2 * 4 + jj;  // global o-tile (prep linear)
            const int ob = T * 16;              // global o-base

            short8 af[4];
            #pragma unroll
            for (int ks = 0; ks < 4; ++ks) af[ks] = wfa[(T * 4 + ks) * 64 + l];
            f32x4 acc[4];
            #pragma unroll
            for (int nt = 0; nt < 4; ++nt) acc[nt] = (f32x4){0.f, 0.f, 0.f, 0.f};
            #pragma unroll
            for (int ks = 0; ks < 4; ++ks) {
                #pragma unroll
                for (int nt = 0; nt < 4; ++nt) {
                    int n = nt * 16 + lr;
                    short8 xf = *(const short8*)(smem + n * 256 +
                                    ((ks * 64 + g * 16) ^ ((n & 7) << 4)));
                    acc[nt] = MFMA(af[ks], xf, acc[nt]);
                }
            }
            f32x4 bv = *(const f32x4*)(qkv_b + ob + g * 4);
            #pragma unroll
            for (int nt = 0; nt < 4; ++nt) acc[nt] += bv;

            if (typ == 0) {            // q -> qkT[ph] cols blk*16.., scaled
                #pragma unroll
                for (int nt = 0; nt < 4; ++nt) {
                    int n = nt * 16 + lr;
                    bfu4 u;
                    #pragma unroll
                    for (int r2 = 0; r2 < 4; ++r2) u[r2] = f2bf(acc[nt][r2] * SCALE);
                    *(bfu4*)(smem + QKO + ph * 8192 + n * 128 +
                             ((blk * 32 + g * 8) ^ ((n & 7) << 4))) = u;
                }
            } else if (typ == 1) {     // k -> qkT[ph] cols 32+blk*16..
                #pragma unroll
                for (int nt = 0; nt < 4; ++nt) {
                    int n = nt * 16 + lr;
                    bfu4 u;
                    #pragma unroll
                    for (int r2 = 0; r2 < 4; ++r2) u[r2] = f2bf(acc[nt][r2]);
                    *(bfu4*)(smem + QKO + ph * 8192 + n * 128 +
                             ((64 + blk * 32 + g * 8) ^ ((n & 7) << 4))) = u;
                }
            } else {                   // v -> Vt[ph][d][m] transposed
                #pragma unroll
                for (int nt = 0; nt < 4; ++nt) {
                    int m = nt * 16 + lr;
                    #pragma unroll
                    for (int r2 = 0; r2 < 4; ++r2) {
                        int d = blk * 16 + g * 4 + r2;
                        *(unsigned short*)(smem + VTO2 + ph * 4096 + d * 128 +
                                           ((m * 2) ^ ((d & 7) << 4))) = f2bf(acc[nt][r2]);
                    }
                }
            }
        }
        __syncthreads();   // B2: qkT/Vt of this pass complete

        // ---- attention: wave (hh, nh); global head hgl ----
        const int hgl = p2 * 2 + hh;
        f32x4 S[2][4];
        {   // C-init: mask + rel-bias (R3-verbatim math; n = nh*32 + ...)
            int pm[4], mc[4]; bool mv[4];
            #pragma unroll
            for (int nt = 0; nt < 4; ++nt) {
                int m = nt * 16 + lr;
                int m_c = m > 48 ? 48 : m;
                int ym = (m_c * 147) >> 10, xm = m_c - ym * 7;
                pm[nt] = ym * 13 + xm; mc[nt] = m_c; mv[nt] = (m < 49);
            }
            const float* mrow = mask + (size_t)wi * 2401;
            #pragma unroll
            for (int mt = 0; mt < 2; ++mt) {
                #pragma unroll
                for (int r2 = 0; r2 < 4; ++r2) {
                    int n = nh * 32 + mt * 16 + g * 4 + r2;
                    int n_c = n > 48 ? 48 : n;
                    int yn = (n_c * 147) >> 10, xn = n_c - yn * 7;
                    int pn = yn * 13 + xn;
                    const float* mr2 = mrow + n_c * 49;
                    #pragma unroll
                    for (int nt = 0; nt < 4; ++nt) {
                        S[mt][nt][r2] = mv[nt]
                            ? (mr2[mc[nt]] + bt[(pn - pm[nt] + 84) * 4 + hgl])
                            : -1e30f;
                    }
                }
            }
        }
        {   // QK^T
            short8 qF[2], kF[4];
            #pragma unroll
            for (int t = 0; t < 2; ++t) {
                int n = nh * 32 + t * 16 + lr;
                qF[t] = *(const short8*)(smem + QKO + hh * 8192 + n * 128 +
                                         ((g * 16) ^ ((n & 7) << 4)));
            }
            #pragma unroll
            for (int t = 0; t < 4; ++t) {
                int m = t * 16 + lr;
                kF[t] = *(const short8*)(smem + QKO + hh * 8192 + m * 128 +
                                         ((64 + g * 16) ^ ((m & 7) << 4)));
            }
            #pragma unroll
            for (int mt = 0; mt < 2; ++mt)
                #pragma unroll
                for (int nt = 0; nt < 4; ++nt)
                    S[mt][nt] = MFMA(qF[mt], kF[nt], S[mt][nt]);
        }
        // softmax over m (regs nt + lanes lr via shfl 1,2,4,8)
        #pragma unroll
        for (int mt = 0; mt < 2; ++mt) {
            f32x4 mx = S[mt][0];
            #pragma unroll
            for (int nt = 1; nt < 4; ++nt)
                #pragma unroll
                for (int r2 = 0; r2 < 4; ++r2) mx[r2] = fmaxf(mx[r2], S[mt][nt][r2]);
            #pragma unroll
            for (int r2 = 0; r2 < 4; ++r2) {
                float v2 = mx[r2];
                v2 = fmaxf(v2, __shfl_xor(v2, 1));
                v2 = fmaxf(v2, __shfl_xor(v2, 2));
                v2 = fmaxf(v2, __shfl_xor(v2, 4));
                v2 = fmaxf(v2, __shfl_xor(v2, 8));
                mx[r2] = v2;
            }
            f32x4 sum = (f32x4){0.f, 0.f, 0.f, 0.f};
            #pragma unroll
            for (int nt = 0; nt < 4; ++nt)
                #pragma unroll
                for (int r2 = 0; r2 < 4; ++r2) {
                    float e = __expf(S[mt][nt][r2] - mx[r2]);
                    S[mt][nt][r2] = e; sum[r2] += e;
                }
            #pragma unroll
            for (int r2 = 0; r2 < 4; ++r2) {
                float s2 = sum[r2];
                s2 += __shfl_xor(s2, 1);
                s2 += __shfl_xor(s2, 2);
                s2 += __shfl_xor(s2, 4);
                s2 += __shfl_xor(s2, 8);
                sum[r2] = 1.0f / s2;
            }
            #pragma unroll
            for (int nt = 0; nt < 4; ++nt)
                #pragma unroll
                for (int r2 = 0; r2 < 4; ++r2) S[mt][nt][r2] *= sum[r2];
        }
        __syncthreads();   // B3: qkT reads done everywhere; region becomes P

        // P -> LDS bf16
        #pragma unroll
        for (int mt = 0; mt < 2; ++mt)
            #pragma unroll
            for (int r2 = 0; r2 < 4; ++r2) {
                int n = nh * 32 + mt * 16 + g * 4 + r2;
                int rowb = QKO + hh * 8192 + n * 128, sw = (n & 7) << 4;
                #pragma unroll
                for (int nt = 0; nt < 4; ++nt) {
                    int m = nt * 16 + lr;
                    *(unsigned short*)(smem + rowb + ((m * 2) ^ sw)) =
                        f2bf(S[mt][nt][r2]);
                }
            }
        __syncthreads();   // B4: P complete

        // PV (O stays in registers)
        f32x4 O[2][2];
        #pragma unroll
        for (int mt = 0; mt < 2; ++mt)
            #pragma unroll
            for (int dt = 0; dt < 2; ++dt) O[mt][dt] = (f32x4){0.f, 0.f, 0.f, 0.f};
        #pragma unroll
        for (int ks2 = 0; ks2 < 2; ++ks2) {
            short8 pf[2], vf[2];
            #pragma unroll
            for (int mt = 0; mt < 2; ++mt) {
                int n = nh * 32 + mt * 16 + lr;
                pf[mt] = *(const short8*)(smem + QKO + hh * 8192 + n * 128 +
                                          ((ks2 * 64 + g * 16) ^ ((n & 7) << 4)));
            }
            #pragma unroll
            for (int dt = 0; dt < 2; ++dt) {
                int d = dt * 16 + lr;
                vf[dt] = *(const short8*)(smem + VTO2 + hh * 4096 + d * 128 +
                                          ((ks2 * 64 + g * 16) ^ ((d & 7) << 4)));
            }
            #pragma unroll
            for (int mt = 0; mt < 2; ++mt)
                #pragma unroll
                for (int dt = 0; dt < 2; ++dt)
                    O[mt][dt] = MFMA(pf[mt], vf[dt], O[mt][dt]);
        }
        #pragma unroll
        for (int mt = 0; mt < 2; ++mt)
            #pragma unroll
            for (int dt = 0; dt < 2; ++dt) Osav[p2][mt][dt] = O[mt][dt];
        __syncthreads();   // B5: P/Vt reads done; regions reusable by next pass
    }

    // ---- aoT[n][c] into [0,16K) (xs dead) ----
    #pragma unroll
    for (int p2 = 0; p2 < 2; ++p2)
        #pragma unroll
        for (int mt = 0; mt < 2; ++mt)
            #pragma unroll
            for (int dt = 0; dt < 2; ++dt) {
                int c = (p2 * 2 + hh) * 32 + dt * 16 + lr;
                #pragma unroll
                for (int r2 = 0; r2 < 4; ++r2) {
                    int n = nh * 32 + mt * 16 + g * 4 + r2;
                    *(unsigned short*)(smem + n * 256 + ((c * 2) ^ ((n & 7) << 4))) =
                        f2bf(Osav[p2][mt][dt][r2]);
                }
            }
    __syncthreads();   // B6

    // ---- proj: wave w owns co [w*32, w*32+32) ----
    f32x4 Pa[4][2];
    #pragma unroll
    for (int mt = 0; mt < 4; ++mt)
        #pragma unroll
        for (int ct = 0; ct < 2; ++ct) Pa[mt][ct] = (f32x4){0.f, 0.f, 0.f, 0.f};
    #pragma unroll
    for (int ks = 0; ks < 4; ++ks) {
        short8 aF[4], bF[2];
        #pragma unroll
        for (int mt = 0; mt < 4; ++mt) {
            int n = mt * 16 + lr;
            aF[mt] = *(const short8*)(smem + n * 256 +
                          ((ks * 64 + g * 16) ^ ((n & 7) << 4)));
        }
        #pragma unroll
        for (int ct = 0; ct < 2; ++ct)
            bF[ct] = wfa[6144 + ((w * 2 + ct) * 4 + ks) * 64 + l];
        #pragma unroll
        for (int mt = 0; mt < 4; ++mt)
            #pragma unroll
            for (int ct = 0; ct < 2; ++ct)
                Pa[mt][ct] = MFMA(aF[mt], bF[ct], Pa[mt][ct]);
    }
    __syncthreads();   // B7: all LDS reads done; whole arena dead

    // ---- NEW: stage output f32 in LDS at the exact global layout [co][n] ----
    {
        float* os = (float*)smem;    // 6272 floats = 25088B (< 40KB)
        #pragma unroll
        for (int ct = 0; ct < 2; ++ct) {
            int co = (w * 2 + ct) * 16 + lr;
            float pb2 = proj_b[co];
            #pragma unroll
            for (int mt = 0; mt < 4; ++mt) {
                int n0 = mt * 16 + g * 4;
                if (mt < 3) {
                    #pragma unroll
                    for (int r2 = 0; r2 < 4; ++r2)
                        os[co * 49 + n0 + r2] = Pa[mt][ct][r2] + pb2;
                } else if (g == 0) {
                    os[co * 49 + 48] = Pa[3][ct][0] + pb2;
                }
            }
        }
    }
    __syncthreads();   // B8: staging complete

    // ---- fully-coalesced linear float4 output copy ----
    {
        const float4* os4 = (const float4*)smem;
        float4* ob4 = (float4*)(out + (size_t)b * 6272);
        for (int i = tid; i < 1568; i += 256) ob4[i] = os4[i];
    }
}

extern "C" void kernel_launch(void* const* d_in, const int* in_sizes, int n_in,
                              void* d_out, int out_size, void* d_ws, size_t ws_size,
                              hipStream_t stream) {
    const float* x      = (const float*)d_in[0];
    const float* mask   = (const float*)d_in[1];
    const float* qkv_w  = (const float*)d_in[2];
    const float* qkv_b  = (const float*)d_in[3];
    const float* proj_w = (const float*)d_in[4];
    const float* proj_b = (const float*)d_in[5];
    const float* btab   = (const float*)d_in[6];
    float* o = (float*)d_out;

    unsigned short* wf = (unsigned short*)d_ws;     // 128KB (R3-proven footprint)

    prep_w<<<256, 256, 0, stream>>>(qkv_w, proj_w, wf);

    (void)hipFuncSetAttribute(reinterpret_cast<const void*>(win_attn_mfma),
                        hipFuncAttributeMaxDynamicSharedMemorySize, LDS_BYTES);
    win_attn_mfma<<<4096, 256, LDS_BYTES, stream>>>(x, mask, qkv_b, proj_b, btab, wf, o);
}

// Round 11
// 180.798 us; speedup vs baseline: 1.6443x; 1.6443x over previous
//
#include <hip/hip_runtime.h>

typedef __attribute__((ext_vector_type(8))) short short8;
typedef __attribute__((ext_vector_type(4))) float f32x4;
typedef __attribute__((ext_vector_type(4))) unsigned short bfu4;

#define MFMA(a, b, c) __builtin_amdgcn_mfma_f32_16x16x32_bf16((a), (b), (c), 0, 0, 0)
#define SCALE 0.17677669529663687f

__device__ __forceinline__ unsigned short f2bf(float f) {
    union { float f; unsigned u; } v; v.f = f;
    unsigned r = v.u + 0x7fffu + ((v.u >> 16) & 1u);
    return (unsigned short)(r >> 16);
}

// ---- prep: R3-verbatim weight fragment layout (128KB in d_ws) ----
__global__ __launch_bounds__(256)
void prep_w(const float* __restrict__ qkv_w, const float* __restrict__ proj_w,
            unsigned short* __restrict__ wf)
{
    int id = blockIdx.x * 256 + threadIdx.x;          // 0..65535
    int j  = id & 7;
    int l  = (id >> 3) & 63;
    int ks = (id >> 9) & 3;
    int row16 = l & 15;
    int kk = ks * 32 + ((l >> 4) << 3) + j;
    if (id < 49152) {
        int mt = id >> 11;                            // 0..23
        wf[id] = f2bf(qkv_w[(mt * 16 + row16) * 128 + kk]);
    } else {
        int mt = (id - 49152) >> 11;                  // 0..7
        wf[id] = f2bf(proj_w[(mt * 16 + row16) * 128 + kk]);
    }
}

// ---- main: one block/window, TWO head-pair passes through 40KB LDS ----
// [0,16K)  xs [64n][128c] bf16 swz ^((n&7)<<4)  -> aoT (same layout) after pass 2
// [16K,32K) qkT per pass: [2 hh][64n][64col] (q cols 0..31, k cols 32..63) -> P
// [32K,40K) Vt per pass: [2 hh][32d][64m] swz ^((d&7)<<4)
// launch_bounds(256,2): VGPR cap 256 — R9/R10's (256,4) capped at 128 and forced
// ~400MB/dispatch of spill traffic (WRITE_SIZE 457-493MB vs 100MB ideal).
#define QKO 16384
#define VTO2 32768
#define LDS_BYTES 40960

__global__ __launch_bounds__(256, 2)
void win_attn_mfma(const float* __restrict__ x, const float* __restrict__ mask,
                   const float* __restrict__ qkv_b, const float* __restrict__ proj_b,
                   const float* __restrict__ bt, const unsigned short* __restrict__ wf,
                   float* __restrict__ out)
{
    extern __shared__ char smem[];
    const int b = blockIdx.x, tid = threadIdx.x;
    const int w = tid >> 6, l = tid & 63, g = l >> 4, lr = l & 15;
    const int wi = b & 63;
    const int hh = w >> 1;          // local head (0..1) within the pass
    const int nh = w & 1;           // n-half (rows nh*32 .. nh*32+31)

    // ---- stage x (float4 loads + f2bf; R3 layout) ----
    {
        const float4* xb4 = (const float4*)(x + (size_t)b * 6272);
        for (int i = tid; i < 1568; i += 256) {
            float4 v4 = xb4[i];
            float vals[4] = {v4.x, v4.y, v4.z, v4.w};
            int r0 = i * 4;
            #pragma unroll
            for (int e = 0; e < 4; ++e) {
                int r = r0 + e;
                int c = (int)(((unsigned)r * 21400u) >> 20);   // r/49, exact for r<6272
                int n = r - c * 49;
                *(unsigned short*)(smem + n * 256 + ((c * 2) ^ ((n & 7) << 4))) =
                    f2bf(vals[e]);
            }
        }
        for (int i = tid; i < 1920; i += 256) {                // zero pad rows 49..63
            int n = 49 + (i >> 7), c = i & 127;
            *(unsigned short*)(smem + n * 256 + ((c * 2) ^ ((n & 7) << 4))) = 0;
        }
    }
    __syncthreads();   // B1

    const short8* wfa = (const short8*)wf;
    f32x4 Osav[2][2][2];   // [pass][mt][dt] — static indices only

    #pragma unroll
    for (int p2 = 0; p2 < 2; ++p2) {
        // ---- phase A: wave w handles parts j = 3w..3w+2 of this pass's 12 ----
        #pragma unroll
        for (int i = 0; i < 3; ++i) {
            const int j = w * 3 + i;            // 0..11
            const int typ = j >> 2;             // 0=q, 1=k, 2=v
            const int jj = j & 3;
            const int ph = jj >> 1;             // local head of this part
            const int blk = jj & 1;             // 16-wide d-block
            const int T = typ * 8 + p2 * 4 + jj;  // global o-tile (prep linear)
            const int ob = T * 16;              // global o-base

            short8 af[4];
            #pragma unroll
            for (int ks = 0; ks < 4; ++ks) af[ks] = wfa[(T * 4 + ks) * 64 + l];
            f32x4 acc[4];
            #pragma unroll
            for (int nt = 0; nt < 4; ++nt) acc[nt] = (f32x4){0.f, 0.f, 0.f, 0.f};
            #pragma unroll
            for (int ks = 0; ks < 4; ++ks) {
                #pragma unroll
                for (int nt = 0; nt < 4; ++nt) {
                    int n = nt * 16 + lr;
                    short8 xf = *(const short8*)(smem + n * 256 +
                                    ((ks * 64 + g * 16) ^ ((n & 7) << 4)));
                    acc[nt] = MFMA(af[ks], xf, acc[nt]);
                }
            }
            f32x4 bv = *(const f32x4*)(qkv_b + ob + g * 4);
            #pragma unroll
            for (int nt = 0; nt < 4; ++nt) acc[nt] += bv;

            if (typ == 0) {            // q -> qkT[ph] cols blk*16.., scaled
                #pragma unroll
                for (int nt = 0; nt < 4; ++nt) {
                    int n = nt * 16 + lr;
                    bfu4 u;
                    #pragma unroll
                    for (int r2 = 0; r2 < 4; ++r2) u[r2] = f2bf(acc[nt][r2] * SCALE);
                    *(bfu4*)(smem + QKO + ph * 8192 + n * 128 +
                             ((blk * 32 + g * 8) ^ ((n & 7) << 4))) = u;
                }
            } else if (typ == 1) {     // k -> qkT[ph] cols 32+blk*16..
                #pragma unroll
                for (int nt = 0; nt < 4; ++nt) {
                    int n = nt * 16 + lr;
                    bfu4 u;
                    #pragma unroll
                    for (int r2 = 0; r2 < 4; ++r2) u[r2] = f2bf(acc[nt][r2]);
                    *(bfu4*)(smem + QKO + ph * 8192 + n * 128 +
                             ((64 + blk * 32 + g * 8) ^ ((n & 7) << 4))) = u;
                }
            } else {                   // v -> Vt[ph][d][m] transposed
                #pragma unroll
                for (int nt = 0; nt < 4; ++nt) {
                    int m = nt * 16 + lr;
                    #pragma unroll
                    for (int r2 = 0; r2 < 4; ++r2) {
                        int d = blk * 16 + g * 4 + r2;
                        *(unsigned short*)(smem + VTO2 + ph * 4096 + d * 128 +
                                           ((m * 2) ^ ((d & 7) << 4))) = f2bf(acc[nt][r2]);
                    }
                }
            }
        }
        __syncthreads();   // B2: qkT/Vt of this pass complete

        // ---- attention: wave (hh, nh); global head hgl ----
        const int hgl = p2 * 2 + hh;
        f32x4 S[2][4];
        {   // C-init: mask + rel-bias
            int pm[4], mc[4]; bool mv[4];
            #pragma unroll
            for (int nt = 0; nt < 4; ++nt) {
                int m = nt * 16 + lr;
                int m_c = m > 48 ? 48 : m;
                int ym = (m_c * 147) >> 10, xm = m_c - ym * 7;
                pm[nt] = ym * 13 + xm; mc[nt] = m_c; mv[nt] = (m < 49);
            }
            const float* mrow = mask + (size_t)wi * 2401;
            #pragma unroll
            for (int mt = 0; mt < 2; ++mt) {
                #pragma unroll
                for (int r2 = 0; r2 < 4; ++r2) {
                    int n = nh * 32 + mt * 16 + g * 4 + r2;
                    int n_c = n > 48 ? 48 : n;
                    int yn = (n_c * 147) >> 10, xn = n_c - yn * 7;
                    int pn = yn * 13 + xn;
                    const float* mr2 = mrow + n_c * 49;
                    #pragma unroll
                    for (int nt = 0; nt < 4; ++nt) {
                        S[mt][nt][r2] = mv[nt]
                            ? (mr2[mc[nt]] + bt[(pn - pm[nt] + 84) * 4 + hgl])
                            : -1e30f;
                    }
                }
            }
        }
        {   // QK^T
            short8 qF[2], kF[4];
            #pragma unroll
            for (int t = 0; t < 2; ++t) {
                int n = nh * 32 + t * 16 + lr;
                qF[t] = *(const short8*)(smem + QKO + hh * 8192 + n * 128 +
                                         ((g * 16) ^ ((n & 7) << 4)));
            }
            #pragma unroll
            for (int t = 0; t < 4; ++t) {
                int m = t * 16 + lr;
                kF[t] = *(const short8*)(smem + QKO + hh * 8192 + m * 128 +
                                         ((64 + g * 16) ^ ((m & 7) << 4)));
            }
            #pragma unroll
            for (int mt = 0; mt < 2; ++mt)
                #pragma unroll
                for (int nt = 0; nt < 4; ++nt)
                    S[mt][nt] = MFMA(qF[mt], kF[nt], S[mt][nt]);
        }
        // softmax over m (regs nt + lanes lr via shfl 1,2,4,8)
        #pragma unroll
        for (int mt = 0; mt < 2; ++mt) {
            f32x4 mx = S[mt][0];
            #pragma unroll
            for (int nt = 1; nt < 4; ++nt)
                #pragma unroll
                for (int r2 = 0; r2 < 4; ++r2) mx[r2] = fmaxf(mx[r2], S[mt][nt][r2]);
            #pragma unroll
            for (int r2 = 0; r2 < 4; ++r2) {
                float v2 = mx[r2];
                v2 = fmaxf(v2, __shfl_xor(v2, 1));
                v2 = fmaxf(v2, __shfl_xor(v2, 2));
                v2 = fmaxf(v2, __shfl_xor(v2, 4));
                v2 = fmaxf(v2, __shfl_xor(v2, 8));
                mx[r2] = v2;
            }
            f32x4 sum = (f32x4){0.f, 0.f, 0.f, 0.f};
            #pragma unroll
            for (int nt = 0; nt < 4; ++nt)
                #pragma unroll
                for (int r2 = 0; r2 < 4; ++r2) {
                    float e = __expf(S[mt][nt][r2] - mx[r2]);
                    S[mt][nt][r2] = e; sum[r2] += e;
                }
            #pragma unroll
            for (int r2 = 0; r2 < 4; ++r2) {
                float s2 = sum[r2];
                s2 += __shfl_xor(s2, 1);
                s2 += __shfl_xor(s2, 2);
                s2 += __shfl_xor(s2, 4);
                s2 += __shfl_xor(s2, 8);
                sum[r2] = 1.0f / s2;
            }
            #pragma unroll
            for (int nt = 0; nt < 4; ++nt)
                #pragma unroll
                for (int r2 = 0; r2 < 4; ++r2) S[mt][nt][r2] *= sum[r2];
        }
        __syncthreads();   // B3: qkT reads done everywhere; region becomes P

        // P -> LDS bf16
        #pragma unroll
        for (int mt = 0; mt < 2; ++mt)
            #pragma unroll
            for (int r2 = 0; r2 < 4; ++r2) {
                int n = nh * 32 + mt * 16 + g * 4 + r2;
                int rowb = QKO + hh * 8192 + n * 128, sw = (n & 7) << 4;
                #pragma unroll
                for (int nt = 0; nt < 4; ++nt) {
                    int m = nt * 16 + lr;
                    *(unsigned short*)(smem + rowb + ((m * 2) ^ sw)) =
                        f2bf(S[mt][nt][r2]);
                }
            }
        __syncthreads();   // B4: P complete

        // PV (O stays in registers)
        f32x4 O[2][2];
        #pragma unroll
        for (int mt = 0; mt < 2; ++mt)
            #pragma unroll
            for (int dt = 0; dt < 2; ++dt) O[mt][dt] = (f32x4){0.f, 0.f, 0.f, 0.f};
        #pragma unroll
        for (int ks2 = 0; ks2 < 2; ++ks2) {
            short8 pf[2], vf[2];
            #pragma unroll
            for (int mt = 0; mt < 2; ++mt) {
                int n = nh * 32 + mt * 16 + lr;
                pf[mt] = *(const short8*)(smem + QKO + hh * 8192 + n * 128 +
                                          ((ks2 * 64 + g * 16) ^ ((n & 7) << 4)));
            }
            #pragma unroll
            for (int dt = 0; dt < 2; ++dt) {
                int d = dt * 16 + lr;
                vf[dt] = *(const short8*)(smem + VTO2 + hh * 4096 + d * 128 +
                                          ((ks2 * 64 + g * 16) ^ ((d & 7) << 4)));
            }
            #pragma unroll
            for (int mt = 0; mt < 2; ++mt)
                #pragma unroll
                for (int dt = 0; dt < 2; ++dt)
                    O[mt][dt] = MFMA(pf[mt], vf[dt], O[mt][dt]);
        }
        #pragma unroll
        for (int mt = 0; mt < 2; ++mt)
            #pragma unroll
            for (int dt = 0; dt < 2; ++dt) Osav[p2][mt][dt] = O[mt][dt];
        __syncthreads();   // B5: P/Vt reads done; regions reusable by next pass
    }

    // ---- aoT[n][c] into [0,16K) (xs dead) ----
    #pragma unroll
    for (int p2 = 0; p2 < 2; ++p2)
        #pragma unroll
        for (int mt = 0; mt < 2; ++mt)
            #pragma unroll
            for (int dt = 0; dt < 2; ++dt) {
                int c = (p2 * 2 + hh) * 32 + dt * 16 + lr;
                #pragma unroll
                for (int r2 = 0; r2 < 4; ++r2) {
                    int n = nh * 32 + mt * 16 + g * 4 + r2;
                    *(unsigned short*)(smem + n * 256 + ((c * 2) ^ ((n & 7) << 4))) =
                        f2bf(Osav[p2][mt][dt][r2]);
                }
            }
    __syncthreads();   // B6

    // ---- proj: wave w owns co [w*32, w*32+32); direct strided stores (R3-clean) ----
    f32x4 Pa[4][2];
    #pragma unroll
    for (int mt = 0; mt < 4; ++mt)
        #pragma unroll
        for (int ct = 0; ct < 2; ++ct) Pa[mt][ct] = (f32x4){0.f, 0.f, 0.f, 0.f};
    #pragma unroll
    for (int ks = 0; ks < 4; ++ks) {
        short8 aF[4], bF[2];
        #pragma unroll
        for (int mt = 0; mt < 4; ++mt) {
            int n = mt * 16 + lr;
            aF[mt] = *(const short8*)(smem + n * 256 +
                          ((ks * 64 + g * 16) ^ ((n & 7) << 4)));
        }
        #pragma unroll
        for (int ct = 0; ct < 2; ++ct)
            bF[ct] = wfa[6144 + ((w * 2 + ct) * 4 + ks) * 64 + l];
        #pragma unroll
        for (int mt = 0; mt < 4; ++mt)
            #pragma unroll
            for (int ct = 0; ct < 2; ++ct)
                Pa[mt][ct] = MFMA(aF[mt], bF[ct], Pa[mt][ct]);
    }
    float* obp = out + (size_t)b * 6272;
    #pragma unroll
    for (int ct = 0; ct < 2; ++ct) {
        int co = (w * 2 + ct) * 16 + lr;
        float pb2 = proj_b[co];
        #pragma unroll
        for (int mt = 0; mt < 4; ++mt) {
            int n0 = mt * 16 + g * 4;
            if (mt < 3) {
                #pragma unroll
                for (int r2 = 0; r2 < 4; ++r2)
                    obp[co * 49 + n0 + r2] = Pa[mt][ct][r2] + pb2;
            } else if (g == 0) {
                obp[co * 49 + 48] = Pa[3][ct][0] + pb2;
            }
        }
    }
}

extern "C" void kernel_launch(void* const* d_in, const int* in_sizes, int n_in,
                              void* d_out, int out_size, void* d_ws, size_t ws_size,
                              hipStream_t stream) {
    const float* x      = (const float*)d_in[0];
    const float* mask   = (const float*)d_in[1];
    const float* qkv_w  = (const float*)d_in[2];
    const float* qkv_b  = (const float*)d_in[3];
    const float* proj_w = (const float*)d_in[4];
    const float* proj_b = (const float*)d_in[5];
    const float* btab   = (const float*)d_in[6];
    float* o = (float*)d_out;

    unsigned short* wf = (unsigned short*)d_ws;     // 128KB (R3-proven footprint)

    prep_w<<<256, 256, 0, stream>>>(qkv_w, proj_w, wf);

    (void)hipFuncSetAttribute(reinterpret_cast<const void*>(win_attn_mfma),
                        hipFuncAttributeMaxDynamicSharedMemorySize, LDS_BYTES);
    win_attn_mfma<<<4096, 256, LDS_BYTES, stream>>>(x, mask, qkv_b, proj_b, btab, wf, o);
}